// Round 1
// baseline (171.692 us; speedup 1.0000x reference)
//
#include <hip/hip_runtime.h>

typedef float float4v __attribute__((ext_vector_type(4)));
typedef short short8  __attribute__((ext_vector_type(8)));

#define TOKENS_PER_BLOCK 256
#define NBLOCKS 512   // 512 * 256 = 131072 tokens

__device__ __forceinline__ short f2bf(float f) {
  unsigned u = __float_as_uint(f);
  unsigned r = (u + 0x7fffu + ((u >> 16) & 1u)) >> 16;  // RNE
  return (short)r;
}

__global__ __launch_bounds__(256, 2)
void tangent_fused(const float* __restrict__ x,
                   const float* __restrict__ U0,
                   const float* __restrict__ W0,
                   const float* __restrict__ dk,
                   const float* __restrict__ bias,
                   float* __restrict__ out)
{
  // LDS: x tile (stride 100 floats), v tile (stride 104, 16B-aligned rows),
  // padded U0/W0 (16x36), Y tile bf16 (stride 520 = 512 + 8 pad)
  __shared__ __align__(16) float xlds[16 * 100];
  __shared__ __align__(16) float vlds[16 * 104];
  __shared__ __align__(16) float u0p[16 * 36];
  __shared__ __align__(16) float w0p[16 * 36];
  __shared__ __align__(16) short ylds[16 * 520];

  const int tid  = threadIdx.x;
  const int lane = tid & 63;
  const int wv   = tid >> 6;

  // ---- one-time: U0/W0 padded into LDS ----
  for (int i = tid; i < 16 * 36; i += 256) { u0p[i] = 0.f; w0p[i] = 0.f; }
  __syncthreads();
  for (int i = tid; i < 496; i += 256) {
    int r = i / 31, c = i % 31;
    u0p[r * 36 + c] = U0[i];
    w0p[r * 36 + c] = W0[i];
  }

  // ---- one-time: dense_kernel -> bf16 B-fragments in registers ----
  // B layout for mfma_f32_16x16x32_bf16: lane holds B[k=(lane>>4)*8+j][n=lane&15]
  const int bn  = lane & 15;
  const int k8  = (lane >> 4) * 8;
  const int ch0 = wv * 32;          // wave w covers channels [32w, 32w+32)
  short8 bfrag[16][2];
#pragma unroll
  for (int kk = 0; kk < 16; ++kk) {
#pragma unroll
    for (int g = 0; g < 2; ++g) {
      int c = ch0 + 16 * g + bn;
      short8 t;
#pragma unroll
      for (int j = 0; j < 8; ++j) {
        int f = kk * 32 + k8 + j;                 // K padded 496 -> 512
        float v = (f < 496) ? dk[f * 128 + c] : 0.f;
        t[j] = f2bf(v);
      }
      bfrag[kk][g] = t;
    }
  }
  const float bias0 = bias[ch0 + bn];
  const float bias1 = bias[ch0 + 16 + bn];
  __syncthreads();

  const int tok16 = tid >> 4;   // token within 16-token tile
  const int tt    = tid & 15;   // lane within token

  const int block_tok0 = blockIdx.x * TOKENS_PER_BLOCK;

  for (int tile = 0; tile < 16; ++tile) {
    const int tbase = block_tok0 + tile * 16;

    // ---- stage x tile: 16 tokens * 96 floats = 384 float4, coalesced ----
    {
      const float4v* xg = (const float4v*)(x + (size_t)tbase * 96);
      {
        int idx = tid;
        float4v v = xg[idx];
        int tk = idx / 24, cl = (idx % 24) * 4;
        *(float4v*)&xlds[tk * 100 + cl] = v;
      }
      {
        int idx = tid + 256;
        if (idx < 384) {
          float4v v = xg[idx];
          int tk = idx / 24, cl = (idx % 24) * 4;
          *(float4v*)&xlds[tk * 100 + cl] = v;
        }
      }
    }
    __syncthreads();

    // ---- phase 1a: v_j = log-map of q_j around p ----
    {
      const float* xr = &xlds[tok16 * 100];
      float p0 = xr[0], p1 = xr[1], p2 = xr[2];
      float* vr = &vlds[tok16 * 104];
#pragma unroll
      for (int rep = 0; rep < 2; ++rep) {
        int jj = tt + rep * 16;                   // 0..30
        if (jj < 31) {
          float q0 = xr[3 + 3 * jj], q1 = xr[4 + 3 * jj], q2 = xr[5 + 3 * jj];
          // cos with non-fused mul/add, same association as np sum -> rounding
          // matches the reference (acos near -1 amplifies cos ulps ~1000x)
          float cs = __fadd_rn(__fadd_rn(__fmul_rn(p0, q0), __fmul_rn(p1, q1)),
                               __fmul_rn(p2, q2));
          cs = fminf(fmaxf(cs, -1.f), 1.f);
          float th  = acosf(cs);
          float fac = (th < 1e-6f) ? 1.f : (th / sinf(th));
          vr[3 * jj + 0] = fac * (q0 - cs * p0);
          vr[3 * jj + 1] = fac * (q1 - cs * p1);
          vr[3 * jj + 2] = fac * (q2 - cs * p2);
        }
      }
      if (tt == 15) { vr[93] = 0.f; vr[94] = 0.f; vr[95] = 0.f; }  // j-pad
    }
    __syncthreads();

    // ---- phase 1b: k/q/w for i = tt, then Y row writes (A-layout, bf16) ----
    {
      const float4v* v4 = (const float4v*)&vlds[tok16 * 104];
      const float4v* u4 = (const float4v*)&u0p[tt * 36];
      const float4v* w4 = (const float4v*)&w0p[tt * 36];
      float k0 = 0, k1 = 0, k2 = 0, q0 = 0, q1 = 0, q2 = 0;
#pragma unroll
      for (int g = 0; g < 8; ++g) {
        float4v a = v4[3 * g], b = v4[3 * g + 1], c = v4[3 * g + 2];
        float4v uu = u4[g], ww = w4[g];
        k0 += uu.x * a.x; k1 += uu.x * a.y; k2 += uu.x * a.z;
        q0 += ww.x * a.x; q1 += ww.x * a.y; q2 += ww.x * a.z;
        k0 += uu.y * a.w; k1 += uu.y * b.x; k2 += uu.y * b.y;
        q0 += ww.y * a.w; q1 += ww.y * b.x; q2 += ww.y * b.y;
        k0 += uu.z * b.z; k1 += uu.z * b.w; k2 += uu.z * c.x;
        q0 += ww.z * b.z; q1 += ww.z * b.w; q2 += ww.z * c.x;
        k0 += uu.w * c.y; k1 += uu.w * c.z; k2 += uu.w * c.w;
        q0 += ww.w * c.y; q1 += ww.w * c.z; q2 += ww.w * c.w;
      }
      float dot = k0 * q0 + k1 * q1 + k2 * q2;
      float sq  = k0 * k0 + k1 * k1 + k2 * k2 + 2.2204460492503131e-16f;
      float fac = fmaxf(-dot, 0.f) / sq;
      float f8  = 0.8f * fac;                 // 0.2*q + 0.8*(q + fac*k)
      float wx = q0 + f8 * k0, wy = q1 + f8 * k1, wz = q2 + f8 * k2;

      // force re-read of v from LDS instead of keeping 24 float4 live
      // across the loop boundary (bfrag already holds 128 VGPRs)
      asm volatile("" ::: "memory");

      short* yrow = &ylds[tok16 * 520];
#pragma unroll
      for (int g = 0; g < 8; ++g) {
        float4v a = v4[3 * g], b = v4[3 * g + 1], c = v4[3 * g + 2];
        float y0 = a.x * wx + a.y * wy + a.z * wz;   // jj = 4g
        float y1 = a.w * wx + b.x * wy + b.y * wz;
        float y2 = b.z * wx + b.w * wy + c.x * wz;
        float y3 = c.y * wx + c.z * wy + c.w * wz;   // g=7: jj=31 -> zero pad f>=496
        yrow[(4 * g + 0) * 16 + tt] = f2bf(y0);
        yrow[(4 * g + 1) * 16 + tt] = f2bf(y1);
        yrow[(4 * g + 2) * 16 + tt] = f2bf(y2);
        yrow[(4 * g + 3) * 16 + tt] = f2bf(y3);
      }
    }
    __syncthreads();

    // ---- phase 2: Y(16x512) @ dk(512x128), bf16 MFMA 16x16x32 ----
    {
      const int am = lane & 15;                 // A row = token
      float4v acc0 = {0.f, 0.f, 0.f, 0.f};
      float4v acc1 = {0.f, 0.f, 0.f, 0.f};
#pragma unroll
      for (int kk = 0; kk < 16; ++kk) {
        short8 af = *(const short8*)&ylds[am * 520 + kk * 32 + k8];
        acc0 = __builtin_amdgcn_mfma_f32_16x16x32_bf16(af, bfrag[kk][0], acc0, 0, 0, 0);
        acc1 = __builtin_amdgcn_mfma_f32_16x16x32_bf16(af, bfrag[kk][1], acc1, 0, 0, 0);
      }
      // C/D layout: col = lane&15, row = (lane>>4)*4 + reg
      const int row4 = (lane >> 4) * 4;
#pragma unroll
      for (int r = 0; r < 4; ++r) {
        size_t o = (size_t)(tbase + row4 + r) * 128 + ch0 + bn;
        out[o]      = acc0[r] + bias0;
        out[o + 16] = acc1[r] + bias1;
      }
    }
    // no trailing barrier: next tile's staging barrier orders ylds reuse
  }
}

extern "C" void kernel_launch(void* const* d_in, const int* in_sizes, int n_in,
                              void* d_out, int out_size, void* d_ws, size_t ws_size,
                              hipStream_t stream) {
  const float* x    = (const float*)d_in[0];
  const float* U0   = (const float*)d_in[1];
  const float* W0   = (const float*)d_in[2];
  const float* dk   = (const float*)d_in[3];
  const float* bias = (const float*)d_in[4];
  float* out = (float*)d_out;
  tangent_fused<<<NBLOCKS, 256, 0, stream>>>(x, U0, W0, dk, bias, out);
}

// Round 2
// 150.633 us; speedup vs baseline: 1.1398x; 1.1398x over previous
//
#include <hip/hip_runtime.h>

typedef float float4v __attribute__((ext_vector_type(4)));
typedef short short8  __attribute__((ext_vector_type(8)));

#define NBLOCKS 512          // 512 blocks * 256 tokens = 131072
#define TOK_PER_BLOCK 256    // 8 tiles of 32 tokens
#define WS_NEEDED 131072     // 16kk * 4k8g * 128ch * 16B

__device__ __forceinline__ short f2bf(float f) {
  unsigned u = __float_as_uint(f);
  return (short)((u + 0x7fffu + ((u >> 16) & 1u)) >> 16);  // RNE
}

// dk (496x128 f32) -> bf16 MFMA B-fragments in ws, K padded to 512.
// ws[(kk*4 + k8g)*128 + c] = short8{ dk_bf16[kk*32+k8g*8+j][c] : j=0..7 }
__global__ void dk_prep(const float* __restrict__ dk, short8* __restrict__ ws) {
  int g = blockIdx.x * 256 + threadIdx.x;     // 8192 total
  int c = g & 127, k8g = (g >> 7) & 3, kk = g >> 9;
  short8 t;
#pragma unroll
  for (int j = 0; j < 8; ++j) {
    int f = kk * 32 + k8g * 8 + j;
    t[j] = (f < 496) ? f2bf(dk[f * 128 + c]) : (short)0;
  }
  ws[g] = t;
}

template<bool USE_WS>
__global__ __launch_bounds__(512, 4)
void tangent_fused(const float* __restrict__ x,
                   const float* __restrict__ U0,
                   const float* __restrict__ W0,
                   const float* __restrict__ dk,
                   const short8* __restrict__ wsdk,
                   const float* __restrict__ bias,
                   float* __restrict__ out)
{
  // 64000 B total -> 2 blocks/CU by LDS; VGPR target 128 -> 4 waves/SIMD
  __shared__ __align__(16) float xlds[32 * 100];
  __shared__ __align__(16) float vlds[32 * 104];
  __shared__ __align__(16) float u0p[16 * 36];
  __shared__ __align__(16) float w0p[16 * 36];
  __shared__ __align__(16) short ylds[32 * 520];   // stride 520: 260dw = 4 mod 32

  const int tid  = threadIdx.x;
  const int lane = tid & 63;
  const int wv   = tid >> 6;          // 8 waves

  // ---- one-time: U0/W0 padded into LDS ----
  if (tid < 576) { u0p[tid] = 0.f; w0p[tid] = 0.f; }
  __syncthreads();
  if (tid < 496) {
    int r = tid / 31, c = tid % 31;
    u0p[r * 36 + c] = U0[tid];
    w0p[r * 36 + c] = W0[tid];
  }

  // ---- one-time: per-wave 16 output channels of dk as bf16 B-fragments ----
  // B layout for mfma_f32_16x16x32_bf16: lane holds B[k=(lane>>4)*8+j][n=lane&15]
  const int bn  = lane & 15;
  const int k8g = lane >> 4;
  const int k8  = k8g * 8;
  const int ch0 = wv * 16;
  short8 bfrag[16];
  if (USE_WS) {
#pragma unroll
    for (int kk = 0; kk < 16; ++kk)
      bfrag[kk] = wsdk[(kk * 4 + k8g) * 128 + ch0 + bn];
  } else {
#pragma unroll
    for (int kk = 0; kk < 16; ++kk) {
      short8 t;
#pragma unroll
      for (int j = 0; j < 8; ++j) {
        int f = kk * 32 + k8 + j;
        t[j] = (f < 496) ? f2bf(dk[f * 128 + ch0 + bn]) : (short)0;
      }
      bfrag[kk] = t;
    }
  }
  const float bias0 = bias[ch0 + bn];
  __syncthreads();

  const int trow = tid >> 4;    // token row within 32-token tile
  const int tt   = tid & 15;    // lane within 16-lane token group (same wave)
  const int block_tok0 = blockIdx.x * TOK_PER_BLOCK;

  for (int tile = 0; tile < 8; ++tile) {
    const int tbase = block_tok0 + tile * 32;

    // ---- stage x tile: 32 tokens * 96 floats = 768 float4, coalesced ----
    {
      const float4v* xg = (const float4v*)(x + (size_t)tbase * 96);
      {
        int idx = tid;
        float4v v = xg[idx];
        *(float4v*)&xlds[(idx / 24) * 100 + (idx % 24) * 4] = v;
      }
      {
        int idx = tid + 512;
        if (idx < 768) {
          float4v v = xg[idx];
          *(float4v*)&xlds[(idx / 24) * 100 + (idx % 24) * 4] = v;
        }
      }
    }
    __syncthreads();

    // ---- phase 1a: v_j = log-map of q_j around p (wave-internal per token) ----
    {
      const float* xr = &xlds[trow * 100];
      float p0 = xr[0], p1 = xr[1], p2 = xr[2];
      float* vr = &vlds[trow * 104];
#pragma unroll
      for (int rep = 0; rep < 2; ++rep) {
        int jj = tt + rep * 16;                   // 0..30
        if (jj < 31) {
          float q0 = xr[3 + 3 * jj], q1 = xr[4 + 3 * jj], q2 = xr[5 + 3 * jj];
          // cos with np's association/rounding (acos near +-1 amplifies ulps)
          float cs = __fadd_rn(__fadd_rn(__fmul_rn(p0, q0), __fmul_rn(p1, q1)),
                               __fmul_rn(p2, q2));
          cs = fminf(fmaxf(cs, -1.f), 1.f);
          float th = acosf(cs);
          // sin(theta) = sqrt((1-cs)(1+cs)); both factors Sterbenz-exact
          float fac = (th < 1e-6f) ? 1.f
                                   : th * rsqrtf((1.f - cs) * (1.f + cs));
          vr[3 * jj + 0] = fac * (q0 - cs * p0);
          vr[3 * jj + 1] = fac * (q1 - cs * p1);
          vr[3 * jj + 2] = fac * (q2 - cs * p2);
        }
      }
      if (tt == 15) { vr[93] = 0.f; vr[94] = 0.f; vr[95] = 0.f; }  // j=31 pad
    }
    // no barrier: 1a->1b dependency is within the 16-lane token group of one
    // wave; DS ops are in-order per wave.

    // ---- phase 1b: k/q/w for i = tt, then Y row writes (MFMA-A layout, bf16) ----
    {
      const float4v* v4 = (const float4v*)&vlds[trow * 104];
      const float4v* u4 = (const float4v*)&u0p[tt * 36];
      const float4v* w4 = (const float4v*)&w0p[tt * 36];
      float k0 = 0, k1 = 0, k2 = 0, q0 = 0, q1 = 0, q2 = 0;
#pragma unroll
      for (int g = 0; g < 8; ++g) {
        float4v a = v4[3 * g], b = v4[3 * g + 1], c = v4[3 * g + 2];
        float4v uu = u4[g], ww = w4[g];
        k0 += uu.x * a.x; k1 += uu.x * a.y; k2 += uu.x * a.z;
        q0 += ww.x * a.x; q1 += ww.x * a.y; q2 += ww.x * a.z;
        k0 += uu.y * a.w; k1 += uu.y * b.x; k2 += uu.y * b.y;
        q0 += ww.y * a.w; q1 += ww.y * b.x; q2 += ww.y * b.y;
        k0 += uu.z * b.z; k1 += uu.z * b.w; k2 += uu.z * c.x;
        q0 += ww.z * b.z; q1 += ww.z * b.w; q2 += ww.z * c.x;
        k0 += uu.w * c.y; k1 += uu.w * c.z; k2 += uu.w * c.w;
        q0 += ww.w * c.y; q1 += ww.w * c.z; q2 += ww.w * c.w;
      }
      float dot = k0 * q0 + k1 * q1 + k2 * q2;
      float sq  = k0 * k0 + k1 * k1 + k2 * k2 + 2.2204460492503131e-16f;
      float f8  = 0.8f * (fmaxf(-dot, 0.f) / sq);   // 0.2q + 0.8(q + fac*k)
      float wx = q0 + f8 * k0, wy = q1 + f8 * k1, wz = q2 + f8 * k2;

      // force re-read of v from LDS (keeping 24 float4 live would blow 128 VGPR)
      asm volatile("" ::: "memory");

      short* yrow = &ylds[trow * 520];
#pragma unroll
      for (int g = 0; g < 8; ++g) {
        float4v a = v4[3 * g], b = v4[3 * g + 1], c = v4[3 * g + 2];
        float y0 = a.x * wx + a.y * wy + a.z * wz;   // jj = 4g
        float y1 = a.w * wx + b.x * wy + b.y * wz;
        float y2 = b.z * wx + b.w * wy + c.x * wz;
        float y3 = c.y * wx + c.z * wy + c.w * wz;   // g=7,r=3: v-pad -> 0
        yrow[(4 * g + 0) * 16 + tt] = f2bf(y0);
        yrow[(4 * g + 1) * 16 + tt] = f2bf(y1);
        yrow[(4 * g + 2) * 16 + tt] = f2bf(y2);
        yrow[(4 * g + 3) * 16 + tt] = f2bf(y3);
      }
    }
    __syncthreads();

    // ---- phase 2: Y(32x512) @ dk(512x16ch/wave), bf16 MFMA 16x16x32 ----
    {
      const int am = lane & 15;
      float4v acc0 = {0.f, 0.f, 0.f, 0.f};
      float4v acc1 = {0.f, 0.f, 0.f, 0.f};
#pragma unroll
      for (int kk = 0; kk < 16; ++kk) {
        short8 a0 = *(const short8*)&ylds[am * 520 + kk * 32 + k8];
        short8 a1 = *(const short8*)&ylds[(16 + am) * 520 + kk * 32 + k8];
        acc0 = __builtin_amdgcn_mfma_f32_16x16x32_bf16(a0, bfrag[kk], acc0, 0, 0, 0);
        acc1 = __builtin_amdgcn_mfma_f32_16x16x32_bf16(a1, bfrag[kk], acc1, 0, 0, 0);
      }
      // C/D layout: col = lane&15, row = (lane>>4)*4 + reg
      const int row4 = k8g * 4;
#pragma unroll
      for (int r = 0; r < 4; ++r) {
        out[(size_t)(tbase + row4 + r) * 128 + ch0 + bn]      = acc0[r] + bias0;
        out[(size_t)(tbase + 16 + row4 + r) * 128 + ch0 + bn] = acc1[r] + bias0;
      }
    }
    // no trailing barrier: next tile's post-stage barrier orders ylds reuse
  }
}

extern "C" void kernel_launch(void* const* d_in, const int* in_sizes, int n_in,
                              void* d_out, int out_size, void* d_ws, size_t ws_size,
                              hipStream_t stream) {
  const float* x    = (const float*)d_in[0];
  const float* U0   = (const float*)d_in[1];
  const float* W0   = (const float*)d_in[2];
  const float* dk   = (const float*)d_in[3];
  const float* bias = (const float*)d_in[4];
  float* out = (float*)d_out;
  if (ws_size >= WS_NEEDED) {
    short8* ws = (short8*)d_ws;
    dk_prep<<<32, 256, 0, stream>>>(dk, ws);
    tangent_fused<true><<<NBLOCKS, 512, 0, stream>>>(x, U0, W0, dk, ws, bias, out);
  } else {
    tangent_fused<false><<<NBLOCKS, 512, 0, stream>>>(x, U0, W0, dk, nullptr, bias, out);
  }
}